// Round 2
// baseline (289.393 us; speedup 1.0000x reference)
//
#include <hip/hip_runtime.h>
#include <hip/hip_bf16.h>

// Max-margin (hinge) criterion, split into two streaming passes to maximize
// memory-level parallelism (the fused wave-per-row version was latency-bound
// at 16% HBM peak: target-scan -> shuffle-broadcast -> cossim-scan formed a
// serial dependency chain inside every wave).
//
//   Pass A: scan one-hot target (int4), hitting thread gathers
//           correct_sim[row] = cossim[row][col]  -> d_ws
//   Pass B: wave per row, stream cossim (float4), hinge-accumulate against
//           correct_sim[row], hierarchical reduce, one atomic per block.

constexpr int   kC      = 2048;       // choices per row
constexpr float kMargin = 0.1f;

// ---------------- Pass A: find correct similarity per row ----------------
__global__ __launch_bounds__(256) void find_correct_sim(
    const float* __restrict__ cossim,
    const int4*  __restrict__ target4,
    float*       __restrict__ correct_sim,
    int total4)
{
    const int stride = gridDim.x * blockDim.x;
    for (int f = blockIdx.x * blockDim.x + threadIdx.x; f < total4; f += stride) {
        int4 v = target4[f];
        if ((v.x | v.y | v.z | v.w) != 0) {      // one-hot: exactly one row hit
            int base = f << 2;                   // flat element index
            int row  = base >> 11;               // / 2048
            int col  = base & (kC - 1);
            const float* crow = cossim + (size_t)row * kC;
            float s;
            if      (v.x == 1) s = crow[col + 0];
            else if (v.y == 1) s = crow[col + 1];
            else if (v.z == 1) s = crow[col + 2];
            else               s = crow[col + 3];
            correct_sim[row] = s;
        }
    }
}

// ---------------- Pass B: hinge sum, wave per row ----------------
__global__ __launch_bounds__(256) void hinge_sum(
    const float* __restrict__ cossim,
    const float* __restrict__ correct_sim,
    float*       __restrict__ out,
    int nrows, float inv_n)
{
    const int lane          = threadIdx.x & 63;
    const int wave_in_block = threadIdx.x >> 6;
    const int row           = blockIdx.x * 4 + wave_in_block;

    float s = 0.0f;
    if (row < nrows) {
        const float sim = correct_sim[row];          // wave-uniform broadcast load
        const float4* c = (const float4*)(cossim + (size_t)row * kC);
        #pragma unroll
        for (int k = 0; k < kC / (64 * 4); ++k) {    // 8 independent float4 loads
            float4 v = c[lane + k * 64];
            s += fmaxf(kMargin + v.x - sim, 0.0f);
            s += fmaxf(kMargin + v.y - sim, 0.0f);
            s += fmaxf(kMargin + v.z - sim, 0.0f);
            s += fmaxf(kMargin + v.w - sim, 0.0f);
        }
        // reference zeroes the correct-choice term, which equals exactly kMargin
        if (lane == 0) s -= kMargin;
    }

    // wave reduce
    #pragma unroll
    for (int off = 32; off > 0; off >>= 1)
        s += __shfl_xor(s, off);

    // block reduce (4 waves) + one atomic per block
    __shared__ float ws[4];
    if (lane == 0) ws[wave_in_block] = s;
    __syncthreads();
    if (threadIdx.x == 0) {
        float b = ws[0] + ws[1] + ws[2] + ws[3];
        atomicAdd(out, b * inv_n);
    }
}

extern "C" void kernel_launch(void* const* d_in, const int* in_sizes, int n_in,
                              void* d_out, int out_size, void* d_ws, size_t ws_size,
                              hipStream_t stream)
{
    const float* cossim = (const float*)d_in[0];
    const int*   target = (const int*)d_in[1];
    float*       out    = (float*)d_out;
    float*       csim   = (float*)d_ws;          // nrows floats of scratch

    const int nrows  = in_sizes[0] / kC;         // 16384
    const int total4 = in_sizes[1] / 4;          // int4 count of target

    // d_out is poisoned with 0xAA before every launch — zero it (graph-legal).
    hipMemsetAsync(out, 0, sizeof(float), stream);

    // Pass A: pure streaming scan of target.
    find_correct_sim<<<2048, 256, 0, stream>>>(cossim, (const int4*)target,
                                               csim, total4);

    // Pass B: wave per row over cossim.
    hinge_sum<<<(nrows + 3) / 4, 256, 0, stream>>>(cossim, csim, out,
                                                   nrows, 1.0f / (float)nrows);
}